// Round 8
// baseline (170.259 us; speedup 1.0000x reference)
//
#include <hip/hip_runtime.h>
#include <hip/hip_bf16.h>

#define HW 4096
#define CIN 192
#define CMID 96

typedef __attribute__((ext_vector_type(8))) short bf16x8;
typedef __attribute__((ext_vector_type(4))) float f32x4;
typedef __attribute__((ext_vector_type(16))) float f32x16;
typedef __attribute__((ext_vector_type(4))) unsigned int u32x4;
typedef __attribute__((ext_vector_type(2))) unsigned int u32x2;

static __device__ __forceinline__ unsigned short f2bf(float f) {
    union { float f; unsigned int u; } v;
    v.f = f;
    unsigned int r = v.u + 0x7fffu + ((v.u >> 16) & 1u);
    return (unsigned short)(r >> 16);
}

static __device__ __forceinline__ void gload16(const void* g, void* l) {
    __builtin_amdgcn_global_load_lds(
        (const __attribute__((address_space(1))) unsigned int*)g,
        (__attribute__((address_space(3))) unsigned int*)l, 16, 0, 0);
}

// (1/64) * log2(e), folded into Q at projection time
#define SCQ (0.015625f * 1.44269504089f)

// ---------------------------------------------------------------------------
// Kernel 0: convert weights to bf16.
// ---------------------------------------------------------------------------
__global__ __launch_bounds__(256) void convw_kernel(
    const float* __restrict__ wq, const float* __restrict__ wk,
    const float* __restrict__ wv, const float* __restrict__ wz,
    unsigned short* __restrict__ wqkvb, unsigned short* __restrict__ wzb)
{
    int idx = blockIdx.x * 256 + threadIdx.x;
    if (idx < 3 * CMID * CIN) {
        int m = idx / (CMID * CIN), r = idx % (CMID * CIN);
        const float* w = (m == 0) ? wq : ((m == 1) ? wk : wv);
        wqkvb[idx] = f2bf(w[r]);
    } else if (idx < 3 * CMID * CIN + CIN * CMID) {
        int r = idx - 3 * CMID * CIN;
        wzb[r] = f2bf(wz[r]);
    }
}

// ---------------------------------------------------------------------------
// Kernel 1: Q/K/V projections (bf16 MFMA).  Unchanged from R7.
// ---------------------------------------------------------------------------
__global__ __launch_bounds__(512) void qkv_kernel(
    const float* __restrict__ x, const float* __restrict__ pe,
    const unsigned short* __restrict__ wqkvb,
    const float* __restrict__ bq, const float* __restrict__ bk,
    const float* __restrict__ bv,
    unsigned short* __restrict__ Q, unsigned short* __restrict__ K,
    unsigned short* __restrict__ V)
{
    const int bid = blockIdx.x;
    const int n = bid & 7, bx = bid >> 3;
    const int i0 = bx * 64, t = threadIdx.x;
    __shared__ unsigned short xt[64 * 200];

    #pragma unroll
    for (int it = 0; it < 2; ++it) {
        int u = t + it * 512;
        if (u < 768) {
            int c0 = (u >> 4) * 4, p0 = (u & 15) * 4;
            float a[4][4];
            #pragma unroll
            for (int cc = 0; cc < 4; ++cc) {
                f32x4 xv = *(const f32x4*)(x + ((size_t)n * CIN + c0 + cc) * HW + i0 + p0);
                f32x4 pv = *(const f32x4*)(pe + (c0 + cc) * 14400 + bx * 120 + p0);
                #pragma unroll
                for (int p = 0; p < 4; ++p) a[cc][p] = xv[p] + pv[p];
            }
            #pragma unroll
            for (int p = 0; p < 4; ++p) {
                unsigned w0, w1;
                asm("v_cvt_pk_bf16_f32 %0, %1, %2" : "=v"(w0) : "v"(a[0][p]), "v"(a[1][p]));
                asm("v_cvt_pk_bf16_f32 %0, %1, %2" : "=v"(w1) : "v"(a[2][p]), "v"(a[3][p]));
                u32x2 wv2 = {w0, w1};
                *(u32x2*)(xt + (p0 + p) * 200 + c0) = wv2;
            }
        }
    }
    __syncthreads();

    const int w = t >> 6, lane = t & 63, l15 = lane & 15, lg = lane >> 4;
    const int wg = w >> 2;
    const int p0 = (w & 3) * 16;

    bf16x8 af[6];
    #pragma unroll
    for (int f = 0; f < 6; ++f)
        af[f] = *(const bf16x8*)(xt + (p0 + l15) * 200 + f * 32 + lg * 8);

    #pragma unroll
    for (int cc = 0; cc < 9; ++cc) {
        const int ct = wg * 9 + cc;
        const int m = ct / 6, c6 = ct % 6;
        f32x4 acc = (f32x4){0.f, 0.f, 0.f, 0.f};
        const unsigned short* wrow = wqkvb + (ct * 16 + l15) * CIN + lg * 8;
        #pragma unroll
        for (int f = 0; f < 6; ++f) {
            bf16x8 wf = *(const bf16x8*)(wrow + f * 32);
            if (m < 2)
                acc = __builtin_amdgcn_mfma_f32_16x16x32_bf16(wf, af[f], acc, 0, 0, 0);
            else
                acc = __builtin_amdgcn_mfma_f32_16x16x32_bf16(af[f], wf, acc, 0, 0, 0);
        }
        if (m < 2) {
            f32x4 bv4 = *(const f32x4*)(((m == 0) ? bq : bk) + c6 * 16 + lg * 4);
            ushort4 pk4;
            if (m == 0) {
                pk4.x = f2bf((acc[0] + bv4[0]) * SCQ);
                pk4.y = f2bf((acc[1] + bv4[1]) * SCQ);
                pk4.z = f2bf((acc[2] + bv4[2]) * SCQ);
                pk4.w = f2bf((acc[3] + bv4[3]) * SCQ);
            } else {
                pk4.x = f2bf(acc[0] + bv4[0]);
                pk4.y = f2bf(acc[1] + bv4[1]);
                pk4.z = f2bf(acc[2] + bv4[2]);
                pk4.w = f2bf(acc[3] + bv4[3]);
            }
            unsigned short* dst = ((m == 0) ? Q : K) + (size_t)n * HW * CMID;
            *(ushort4*)(dst + (size_t)(i0 + p0 + l15) * CMID + c6 * 16 + lg * 4) = pk4;
        } else {
            const float bias = bv[c6 * 16 + l15];
            ushort4 pk4;
            pk4.x = f2bf(acc[0] + bias); pk4.y = f2bf(acc[1] + bias);
            pk4.z = f2bf(acc[2] + bias); pk4.w = f2bf(acc[3] + bias);
            *(ushort4*)(V + (size_t)n * CMID * HW + (size_t)(c6 * 16 + l15) * HW
                          + i0 + p0 + lg * 4) = pk4;
        }
    }
}

// ---------------------------------------------------------------------------
// Kernel 2: attention core.  32 q-rows/wave, 4 blocks/CU (40 KB LDS), grid
// 1024 all-resident with n==XCD.  K double-buffered 32-j tiles, V double-
// buffered 64-j windows.  Counted vmcnt(3)/vmcnt(0) + raw s_barrier.
// In-register softmax; permlane32_swap; MFMA row-sums.
// ---------------------------------------------------------------------------
__global__ __launch_bounds__(256, 4) void attn_kernel(
    const unsigned short* __restrict__ Q, const unsigned short* __restrict__ K,
    const unsigned short* __restrict__ V,
    unsigned short* __restrict__ zp, float* __restrict__ lp)
{
    const int bid = blockIdx.x;           // 1024 = 8 n * 32 iblk * 4 js
    const int n    = bid & 7;             // n == XCD
    const int iblk = (bid >> 3) & 31;
    const int js   = bid >> 8;            // 0..3

    const int t = threadIdx.x, w = t >> 6, lane = t & 63;
    const int l31 = lane & 31, hi = lane >> 5;
    const int ib = iblk * 128 + w * 32;   // 32 q-rows per wave

    __shared__ unsigned short Ks[2][32 * 128];  // 16 KB
    __shared__ unsigned short Vs[2][96 * 64];   // 24 KB  (total 40960 B)

    const unsigned short* Qb = Q + (size_t)n * HW * CMID;
    const unsigned short* Kb = K + (size_t)n * HW * CMID;
    const unsigned short* Vb = V + (size_t)n * CMID * HW;

    // Q as B-frag: col = i = l31, k = kc*16 + hi*8 + e
    bf16x8 qf[6];
    #pragma unroll
    for (int kc = 0; kc < 6; ++kc)
        qf[kc] = *(const bf16x8*)(Qb + (size_t)(ib + l31) * CMID + kc * 16 + hi * 8);

    // staging source offsets, pre-swizzled (involution: granule ^= row&7)
    int ksoff[2], vsoff[3];
    #pragma unroll
    for (int s = 0; s < 2; ++s) {
        int row = 4 * (w * 2 + s) + (lane >> 4);         // 0..31
        ksoff[s] = row * CMID + (((lane & 15) ^ (row & 7)) * 8);
    }
    #pragma unroll
    for (int s = 0; s < 3; ++s) {
        int c = 8 * (w * 3 + s) + (lane >> 3);           // 0..95
        vsoff[s] = c * HW + (((lane & 7) ^ (c & 7)) * 8);
    }

    const int j00 = js * 1024;

#define STAGE_K(TILE, KB) do {                                                 \
    _Pragma("unroll") for (int s = 0; s < 2; ++s)                              \
        gload16(Kb + (size_t)(j00 + (TILE) * 32) * CMID + ksoff[s],            \
                &Ks[KB][(w * 2 + s) * 512]);                                   \
} while (0)
#define STAGE_V(WND, VB) do {                                                  \
    _Pragma("unroll") for (int s = 0; s < 3; ++s)                              \
        gload16(Vb + (size_t)(j00 + (WND) * 64) + vsoff[s],                    \
                &Vs[VB][(w * 3 + s) * 512]);                                   \
} while (0)

    f32x16 O[3], Lon;
    #pragma unroll
    for (int e = 0; e < 16; ++e) { O[0][e] = 0.f; O[1][e] = 0.f; O[2][e] = 0.f; Lon[e] = 0.f; }

    bf16x8 onef;
    #pragma unroll
    for (int e = 0; e < 8; ++e) onef[e] = (short)0x3F80;  // bf16 1.0

    STAGE_K(0, 0);
    STAGE_V(0, 0);
    asm volatile("s_waitcnt vmcnt(0)" ::: "memory");
    __builtin_amdgcn_s_barrier();

#define BODY(KBUF, VBUF, VHALF) do {                                           \
    const unsigned short* Kc = &Ks[KBUF][0];                                   \
    const unsigned short* Vc = &Vs[VBUF][0];                                   \
    f32x16 sacc;                                                               \
    _Pragma("unroll") for (int e = 0; e < 16; ++e) sacc[e] = 0.f;              \
    __builtin_amdgcn_s_setprio(1);                                             \
    _Pragma("unroll") for (int kc = 0; kc < 6; ++kc) {                         \
        bf16x8 kf = *(const bf16x8*)(Kc + l31 * 128 +                          \
                      (((kc * 2 + hi) ^ (l31 & 7)) << 3));                     \
        sacc = __builtin_amdgcn_mfma_f32_32x32x16_bf16(kf, qf[kc], sacc, 0, 0, 0); \
    }                                                                          \
    __builtin_amdgcn_s_setprio(0);                                             \
    unsigned pkk[4][2];                                                        \
    _Pragma("unroll") for (int q = 0; q < 4; ++q)                              \
        _Pragma("unroll") for (int rp = 0; rp < 2; ++rp) {                     \
            float lo = __builtin_exp2f(sacc[q * 4 + 2 * rp]);                  \
            float hh = __builtin_exp2f(sacc[q * 4 + 2 * rp + 1]);              \
            asm("v_cvt_pk_bf16_f32 %0, %1, %2"                                 \
                : "=v"(pkk[q][rp]) : "v"(lo), "v"(hh));                        \
        }                                                                      \
    u32x4 pfu[2];                                                              \
    _Pragma("unroll") for (int jc = 0; jc < 2; ++jc) {                         \
        unsigned x0 = pkk[2 * jc][0], y0 = pkk[2 * jc + 1][0];                 \
        unsigned x1 = pkk[2 * jc][1], y1 = pkk[2 * jc + 1][1];                 \
        asm("v_permlane32_swap_b32 %0, %1" : "+v"(y0), "+v"(x0));              \
        asm("v_permlane32_swap_b32 %0, %1" : "+v"(y1), "+v"(x1));              \
        pfu[jc][0] = x0; pfu[jc][1] = x1;                                      \
        pfu[jc][2] = y0; pfu[jc][3] = y1;                                      \
    }                                                                          \
    __builtin_amdgcn_s_setprio(1);                                             \
    _Pragma("unroll") for (int jc = 0; jc < 2; ++jc) {                         \
        bf16x8 pa = __builtin_bit_cast(bf16x8, pfu[jc]);                       \
        _Pragma("unroll") for (int cc = 0; cc < 3; ++cc) {                     \
            bf16x8 vf = *(const bf16x8*)(Vc + (cc * 32 + l31) * 64 +           \
                          ((((VHALF) * 4 + jc * 2 + hi) ^ (l31 & 7)) << 3));   \
            O[cc] = __builtin_amdgcn_mfma_f32_32x32x16_bf16(pa, vf, O[cc], 0, 0, 0); \
        }                                                                      \
        Lon = __builtin_amdgcn_mfma_f32_32x32x16_bf16(pa, onef, Lon, 0, 0, 0); \
    }                                                                          \
    __builtin_amdgcn_s_setprio(0);                                             \
} while (0)

    for (int tt = 0; tt < 32; tt += 2) {
        // ---- even: stage K(tt+1)->buf1^, V(w+1); compute tile tt
        {
            STAGE_K(tt + 1, (tt + 1) & 1);
            const int wn = (tt >> 1) + 1;
            const int pfw = (wn < 16) ? wn : 15;
            STAGE_V(pfw, wn & 1);
            BODY(tt & 1, (tt >> 1) & 1, 0);
            asm volatile("s_waitcnt vmcnt(3)" ::: "memory");  // K(tt+1) landed
            __builtin_amdgcn_s_barrier();
        }
        // ---- odd: stage K(tt+2); compute tile tt+1
        {
            const int pfk = (tt + 2 < 32) ? tt + 2 : 31;
            STAGE_K(pfk, (tt + 2) & 1);
            BODY((tt + 1) & 1, (tt >> 1) & 1, 1);
            asm volatile("s_waitcnt vmcnt(0)" ::: "memory");  // K(tt+2)+V(w+1)
            __builtin_amdgcn_s_barrier();
        }
    }
#undef BODY
#undef STAGE_K
#undef STAGE_V

    // ---- epilogue: unnormalized O (bf16) + row sums (Lon col 0)
    unsigned short* zb = zp + ((size_t)js * 8 + n) * HW * CMID;
    #pragma unroll
    for (int cc = 0; cc < 3; ++cc)
        #pragma unroll
        for (int r = 0; r < 16; ++r) {
            int i = ib + (r & 3) + 8 * (r >> 2) + 4 * hi;
            zb[(size_t)i * CMID + cc * 32 + l31] = f2bf(O[cc][r]);
        }

    if (l31 == 0) {
        float* lb = lp + ((size_t)js * 8 + n) * HW;
        #pragma unroll
        for (int r = 0; r < 16; ++r) {
            int i = ib + (r & 3) + 8 * (r >> 2) + 4 * hi;
            lb[i] = Lon[r];
        }
    }
}

// ---------------------------------------------------------------------------
// Kernel 3: combine 4 j-slices, normalize, project back (MFMA), residual.
// Unchanged from R7.
// ---------------------------------------------------------------------------
__global__ __launch_bounds__(256) void zproj_kernel(
    const unsigned short* __restrict__ zp, const float* __restrict__ lp,
    const unsigned short* __restrict__ wzb, const float* __restrict__ bz,
    const float* __restrict__ x, const float* __restrict__ pe,
    float* __restrict__ out)
{
    const int bid = blockIdx.x;
    const int n = bid & 7, bx = bid >> 3;
    const int i0 = bx * 64, t = threadIdx.x;
    __shared__ unsigned short zt[64 * 104];
    __shared__ float ll[64];

    if (t < 64) {
        float s = 0.f;
        #pragma unroll
        for (int sl = 0; sl < 4; ++sl)
            s += lp[(size_t)sl * 8 * HW + (size_t)n * HW + i0 + t];
        ll[t] = 1.f / s;
    }
    __syncthreads();

    #pragma unroll
    for (int u = 0; u < 3; ++u) {
        int unit = t + u * 256;
        int i = unit / 12, g = unit % 12;
        size_t gidx = ((size_t)n * HW + i0 + i) * CMID + g * 8;
        float a[8];
        #pragma unroll
        for (int e = 0; e < 8; ++e) a[e] = 0.f;
        #pragma unroll
        for (int sl = 0; sl < 4; ++sl) {
            u32x4 wv = *(const u32x4*)(zp + (size_t)sl * 8 * HW * CMID + gidx);
            #pragma unroll
            for (int k = 0; k < 4; ++k) {
                union { unsigned u; float f; } lo, hi2;
                lo.u = wv[k] << 16;
                hi2.u = wv[k] & 0xffff0000u;
                a[2 * k]     += lo.f;
                a[2 * k + 1] += hi2.f;
            }
        }
        float li = ll[i];
        unsigned ww[4];
        #pragma unroll
        for (int k = 0; k < 4; ++k) {
            float p0 = a[2 * k] * li, p1 = a[2 * k + 1] * li;
            asm("v_cvt_pk_bf16_f32 %0, %1, %2" : "=v"(ww[k]) : "v"(p0), "v"(p1));
        }
        u32x4 wv4 = {ww[0], ww[1], ww[2], ww[3]};
        *(u32x4*)(zt + i * 104 + g * 8) = wv4;
    }
    __syncthreads();

    const int w = t >> 6, lane = t & 63, l15 = lane & 15, lg = lane >> 4;
    const int p0 = w * 16;

    bf16x8 af[3];
    #pragma unroll
    for (int f = 0; f < 3; ++f)
        af[f] = *(const bf16x8*)(zt + (p0 + l15) * 104 + f * 32 + lg * 8);

    #pragma unroll
    for (int ct = 0; ct < 12; ++ct) {
        f32x4 acc = (f32x4){0.f, 0.f, 0.f, 0.f};
        const unsigned short* wrow = wzb + (ct * 16 + l15) * CMID + lg * 8;
        #pragma unroll
        for (int f = 0; f < 3; ++f) {
            bf16x8 wf = *(const bf16x8*)(wrow + f * 32);
            acc = __builtin_amdgcn_mfma_f32_16x16x32_bf16(af[f], wf, acc, 0, 0, 0);
        }
        const int co = ct * 16 + l15;
        const int ibase = i0 + p0 + lg * 4;
        size_t xa = ((size_t)n * CIN + co) * HW + ibase;
        f32x4 xv = *(const f32x4*)(x + xa);
        f32x4 pv = *(const f32x4*)(pe + co * 14400 + bx * 120 + p0 + lg * 4);
        const float bias = bz[co];
        f32x4 o;
        #pragma unroll
        for (int r = 0; r < 4; ++r) o[r] = xv[r] + pv[r] + acc[r] + bias;
        *(f32x4*)(out + xa) = o;
    }
}

// ---------------------------------------------------------------------------
extern "C" void kernel_launch(void* const* d_in, const int* in_sizes, int n_in,
                              void* d_out, int out_size, void* d_ws, size_t ws_size,
                              hipStream_t stream) {
    const float* x  = (const float*)d_in[0];
    const float* pe = (const float*)d_in[1];
    const float* wq = (const float*)d_in[2];
    const float* bq = (const float*)d_in[3];
    const float* wk = (const float*)d_in[4];
    const float* bk = (const float*)d_in[5];
    const float* wv = (const float*)d_in[6];
    const float* bv = (const float*)d_in[7];
    const float* wz = (const float*)d_in[8];
    const float* bz = (const float*)d_in[9];
    float* out = (float*)d_out;

    char* ws = (char*)d_ws;
    // ws layout (bytes) — JS=4 (R5/R7-proven):
    //        0: wqkvb bf16 [288][192]          110,592 (pad 131072)
    //   131072: wzb   bf16 [192][96]            36,864 (pad 65536)
    //   196608: Q bf16 [8][4096][96]          6,291,456
    //  6488064: K bf16                        6,291,456
    // 12779520: V^T bf16 [8][96][4096]        6,291,456
    // 19070976: zp bf16 [4][8][4096][96]     25,165,824
    // 44236800: lp f32 [4][8][4096]             524,288   (end 44,761,088)
    unsigned short* wqkvb = (unsigned short*)(ws);
    unsigned short* wzb   = (unsigned short*)(ws + 131072);
    unsigned short* Qb    = (unsigned short*)(ws + 196608);
    unsigned short* Kb    = (unsigned short*)(ws + 6488064);
    unsigned short* Vb    = (unsigned short*)(ws + 12779520);
    unsigned short* zpb   = (unsigned short*)(ws + 19070976);
    float*          lpb   = (float*)(ws + 44236800);

    convw_kernel<<<288, 256, 0, stream>>>(wq, wk, wv, wz, wqkvb, wzb);
    qkv_kernel<<<512, 512, 0, stream>>>(x, pe, wqkvb, bq, bk, bv, Qb, Kb, Vb);
    attn_kernel<<<1024, 256, 0, stream>>>(Qb, Kb, Vb, zpb, lpb);
    zproj_kernel<<<512, 256, 0, stream>>>(zpb, lpb, wzb, bz, x, pe, out);
}

// Round 9
// 126.703 us; speedup vs baseline: 1.3438x; 1.3438x over previous
//
#include <hip/hip_runtime.h>
#include <hip/hip_bf16.h>

#define HW 4096
#define CIN 192
#define CMID 96

typedef __attribute__((ext_vector_type(8))) short bf16x8;
typedef __attribute__((ext_vector_type(4))) float f32x4;
typedef __attribute__((ext_vector_type(16))) float f32x16;
typedef __attribute__((ext_vector_type(4))) unsigned int u32x4;
typedef __attribute__((ext_vector_type(2))) unsigned int u32x2;

static __device__ __forceinline__ unsigned short f2bf(float f) {
    union { float f; unsigned int u; } v;
    v.f = f;
    unsigned int r = v.u + 0x7fffu + ((v.u >> 16) & 1u);
    return (unsigned short)(r >> 16);
}

static __device__ __forceinline__ void gload16(const void* g, void* l) {
    __builtin_amdgcn_global_load_lds(
        (const __attribute__((address_space(1))) unsigned int*)g,
        (__attribute__((address_space(3))) unsigned int*)l, 16, 0, 0);
}

// (1/64) * log2(e), folded into Q at projection time
#define SCQ (0.015625f * 1.44269504089f)

// ---------------------------------------------------------------------------
// Kernel 0: convert weights to bf16.
// ---------------------------------------------------------------------------
__global__ __launch_bounds__(256) void convw_kernel(
    const float* __restrict__ wq, const float* __restrict__ wk,
    const float* __restrict__ wv, const float* __restrict__ wz,
    unsigned short* __restrict__ wqkvb, unsigned short* __restrict__ wzb)
{
    int idx = blockIdx.x * 256 + threadIdx.x;
    if (idx < 3 * CMID * CIN) {
        int m = idx / (CMID * CIN), r = idx % (CMID * CIN);
        const float* w = (m == 0) ? wq : ((m == 1) ? wk : wv);
        wqkvb[idx] = f2bf(w[r]);
    } else if (idx < 3 * CMID * CIN + CIN * CMID) {
        int r = idx - 3 * CMID * CIN;
        wzb[r] = f2bf(wz[r]);
    }
}

// ---------------------------------------------------------------------------
// Kernel 1: Q/K/V projections (bf16 MFMA).  R6-proven config: 2-D grid,
// 512 threads, vectorized f32x4 staging.  Q pre-scaled by SCQ.
// Q,K out [n][i][96]; V out [n][96][i].
// ---------------------------------------------------------------------------
__global__ __launch_bounds__(512) void qkv_kernel(
    const float* __restrict__ x, const float* __restrict__ pe,
    const unsigned short* __restrict__ wqkvb,
    const float* __restrict__ bq, const float* __restrict__ bk,
    const float* __restrict__ bv,
    unsigned short* __restrict__ Q, unsigned short* __restrict__ K,
    unsigned short* __restrict__ V)
{
    const int n = blockIdx.y, bx = blockIdx.x, i0 = bx * 64, t = threadIdx.x;
    __shared__ unsigned short xt[64 * 200];

    // stage bf16(x+pe) transposed [pixel][c], vectorized f32x4 + cvt_pk
    #pragma unroll
    for (int it = 0; it < 6; ++it) {
        int q = t + it * 512;                 // 0..3071 quads
        int c = q >> 4, il4 = (q & 15) << 2;
        f32x4 xv = *(const f32x4*)(x + ((size_t)n * CIN + c) * HW + i0 + il4);
        f32x4 pv = *(const f32x4*)(pe + c * 14400 + bx * 120 + il4);
        float a0 = xv[0] + pv[0], a1 = xv[1] + pv[1];
        float a2 = xv[2] + pv[2], a3 = xv[3] + pv[3];
        unsigned w01, w23;
        asm("v_cvt_pk_bf16_f32 %0, %1, %2" : "=v"(w01) : "v"(a0), "v"(a1));
        asm("v_cvt_pk_bf16_f32 %0, %1, %2" : "=v"(w23) : "v"(a2), "v"(a3));
        xt[(il4 + 0) * 200 + c] = (unsigned short)w01;
        xt[(il4 + 1) * 200 + c] = (unsigned short)(w01 >> 16);
        xt[(il4 + 2) * 200 + c] = (unsigned short)w23;
        xt[(il4 + 3) * 200 + c] = (unsigned short)(w23 >> 16);
    }
    __syncthreads();

    const int w = t >> 6, lane = t & 63, l15 = lane & 15, lg = lane >> 4;
    const int wg = w >> 2;            // 0: ct 0-8, 1: ct 9-17
    const int p0 = (w & 3) * 16;      // pixel group

    bf16x8 af[6];
    #pragma unroll
    for (int f = 0; f < 6; ++f)
        af[f] = *(const bf16x8*)(xt + (p0 + l15) * 200 + f * 32 + lg * 8);

    #pragma unroll
    for (int cc = 0; cc < 9; ++cc) {
        const int ct = wg * 9 + cc;
        const int m = ct / 6, c6 = ct % 6;
        f32x4 acc = (f32x4){0.f, 0.f, 0.f, 0.f};
        const unsigned short* wrow = wqkvb + (ct * 16 + l15) * CIN + lg * 8;
        #pragma unroll
        for (int f = 0; f < 6; ++f) {
            bf16x8 wf = *(const bf16x8*)(wrow + f * 32);
            if (m < 2)
                acc = __builtin_amdgcn_mfma_f32_16x16x32_bf16(wf, af[f], acc, 0, 0, 0);
            else
                acc = __builtin_amdgcn_mfma_f32_16x16x32_bf16(af[f], wf, acc, 0, 0, 0);
        }
        if (m < 2) {
            f32x4 bv4 = *(const f32x4*)(((m == 0) ? bq : bk) + c6 * 16 + lg * 4);
            ushort4 pk4;
            if (m == 0) {
                pk4.x = f2bf((acc[0] + bv4[0]) * SCQ);
                pk4.y = f2bf((acc[1] + bv4[1]) * SCQ);
                pk4.z = f2bf((acc[2] + bv4[2]) * SCQ);
                pk4.w = f2bf((acc[3] + bv4[3]) * SCQ);
            } else {
                pk4.x = f2bf(acc[0] + bv4[0]);
                pk4.y = f2bf(acc[1] + bv4[1]);
                pk4.z = f2bf(acc[2] + bv4[2]);
                pk4.w = f2bf(acc[3] + bv4[3]);
            }
            unsigned short* dst = ((m == 0) ? Q : K) + (size_t)n * HW * CMID;
            *(ushort4*)(dst + (size_t)(i0 + p0 + l15) * CMID + c6 * 16 + lg * 4) = pk4;
        } else {
            const float bias = bv[c6 * 16 + l15];
            ushort4 pk4;
            pk4.x = f2bf(acc[0] + bias); pk4.y = f2bf(acc[1] + bias);
            pk4.z = f2bf(acc[2] + bias); pk4.w = f2bf(acc[3] + bias);
            *(ushort4*)(V + (size_t)n * CMID * HW + (size_t)(c6 * 16 + l15) * HW
                          + i0 + p0 + lg * 4) = pk4;
        }
    }
}

// ---------------------------------------------------------------------------
// Kernel 2: attention core (R5/R7-proven config, verbatim).  64 q-rows/wave,
// 32-j K tiles (triple-buffered, distance-2 prefetch), 64-j V windows
// (double-buffered).  Counted vmcnt(5)/(2) + raw s_barrier.  In-register
// softmax; permlane32_swap; MFMA row-sums.
// ---------------------------------------------------------------------------
__global__ __launch_bounds__(256, 2) void attn_kernel(
    const unsigned short* __restrict__ Q, const unsigned short* __restrict__ K,
    const unsigned short* __restrict__ V,
    unsigned short* __restrict__ zp, float* __restrict__ lp)
{
    const int bid = blockIdx.x;           // 512 = 8 n * 16 iblk * 4 js
    const int n    = bid & 7;             // n == XCD: K/V L2-resident per XCD
    const int iblk = (bid >> 3) & 15;
    const int js   = bid >> 7;            // 0..3

    const int t = threadIdx.x, w = t >> 6, lane = t & 63;
    const int l31 = lane & 31, hi = lane >> 5;
    const int ib = iblk * 256 + w * 64;   // first of 64 q-rows for this wave

    __shared__ unsigned short Ks[3][32 * 128];  // 3 x 8 KB
    __shared__ unsigned short Vs[2][96 * 64];   // 2 x 12 KB

    const unsigned short* Qb = Q + (size_t)n * HW * CMID;
    const unsigned short* Kb = K + (size_t)n * HW * CMID;
    const unsigned short* Vb = V + (size_t)n * CMID * HW;

    // Q as B-frag: col = i, k = kc*16 + hi*8 + e
    bf16x8 qf[2][6];
    #pragma unroll
    for (int is = 0; is < 2; ++is)
        #pragma unroll
        for (int kc = 0; kc < 6; ++kc)
            qf[is][kc] = *(const bf16x8*)(Qb + (size_t)(ib + is * 32 + l31) * CMID
                                            + kc * 16 + hi * 8);

    // staging source offsets, pre-swizzled (involution: granule ^= row&7)
    int ksoff[2], vsoff[3];
    #pragma unroll
    for (int s = 0; s < 2; ++s) {
        int row = 8 * w + 4 * s + (lane >> 4);           // 0..31
        ksoff[s] = row * CMID + (((lane & 15) ^ (row & 7)) * 8);
    }
    #pragma unroll
    for (int s = 0; s < 3; ++s) {
        int c = 8 * (w * 3 + s) + (lane >> 3);           // 0..95
        vsoff[s] = c * HW + (((lane & 7) ^ (c & 7)) * 8);
    }

    const int j00 = js * 1024;

#define STAGE_K(TILE, KB) do {                                                 \
    _Pragma("unroll") for (int s = 0; s < 2; ++s)                              \
        gload16(Kb + (size_t)(j00 + (TILE) * 32) * CMID + ksoff[s],            \
                &Ks[KB][(w * 2 + s) * 512]);                                   \
} while (0)
#define STAGE_V(WND, VB) do {                                                  \
    _Pragma("unroll") for (int s = 0; s < 3; ++s)                              \
        gload16(Vb + (size_t)(j00 + (WND) * 64) + vsoff[s],                    \
                &Vs[VB][(w * 3 + s) * 512]);                                   \
} while (0)

    f32x16 O[2][3], Lon[2];
    #pragma unroll
    for (int is = 0; is < 2; ++is) {
        #pragma unroll
        for (int cc = 0; cc < 3; ++cc)
            #pragma unroll
            for (int e = 0; e < 16; ++e) O[is][cc][e] = 0.f;
        #pragma unroll
        for (int e = 0; e < 16; ++e) Lon[is][e] = 0.f;
    }

    bf16x8 onef;
    #pragma unroll
    for (int e = 0; e < 8; ++e) onef[e] = (short)0x3F80;  // bf16 1.0

    STAGE_K(0, 0);
    STAGE_K(1, 1);
    STAGE_V(0, 0);
    asm volatile("s_waitcnt vmcnt(0)" ::: "memory");
    __builtin_amdgcn_s_barrier();

#define BODY(KBUF, VBUF, VHALF) do {                                           \
    const unsigned short* Kc = &Ks[KBUF][0];                                   \
    const unsigned short* Vc = &Vs[VBUF][0];                                   \
    f32x16 s0, s1;                                                             \
    _Pragma("unroll") for (int e = 0; e < 16; ++e) { s0[e] = 0.f; s1[e] = 0.f; } \
    __builtin_amdgcn_s_setprio(1);                                             \
    _Pragma("unroll") for (int kc = 0; kc < 6; ++kc) {                         \
        bf16x8 kf = *(const bf16x8*)(Kc + l31 * 128 +                          \
                      (((kc * 2 + hi) ^ (l31 & 7)) << 3));                     \
        s0 = __builtin_amdgcn_mfma_f32_32x32x16_bf16(kf, qf[0][kc], s0, 0, 0, 0); \
        s1 = __builtin_amdgcn_mfma_f32_32x32x16_bf16(kf, qf[1][kc], s1, 0, 0, 0); \
    }                                                                          \
    __builtin_amdgcn_s_setprio(0);                                             \
    unsigned pkk[2][4][2];                                                     \
    _Pragma("unroll") for (int q = 0; q < 4; ++q)                              \
        _Pragma("unroll") for (int rp = 0; rp < 2; ++rp) {                     \
            float lo0 = __builtin_exp2f(s0[q * 4 + 2 * rp]);                   \
            float hh0 = __builtin_exp2f(s0[q * 4 + 2 * rp + 1]);               \
            float lo1 = __builtin_exp2f(s1[q * 4 + 2 * rp]);                   \
            float hh1 = __builtin_exp2f(s1[q * 4 + 2 * rp + 1]);               \
            asm("v_cvt_pk_bf16_f32 %0, %1, %2"                                 \
                : "=v"(pkk[0][q][rp]) : "v"(lo0), "v"(hh0));                   \
            asm("v_cvt_pk_bf16_f32 %0, %1, %2"                                 \
                : "=v"(pkk[1][q][rp]) : "v"(lo1), "v"(hh1));                   \
        }                                                                      \
    u32x4 pfu[2][2];                                                           \
    _Pragma("unroll") for (int is = 0; is < 2; ++is)                           \
        _Pragma("unroll") for (int jc = 0; jc < 2; ++jc) {                     \
            unsigned x0 = pkk[is][2 * jc][0], y0 = pkk[is][2 * jc + 1][0];     \
            unsigned x1 = pkk[is][2 * jc][1], y1 = pkk[is][2 * jc + 1][1];     \
            asm("v_permlane32_swap_b32 %0, %1" : "+v"(y0), "+v"(x0));          \
            asm("v_permlane32_swap_b32 %0, %1" : "+v"(y1), "+v"(x1));          \
            pfu[is][jc][0] = x0; pfu[is][jc][1] = x1;                          \
            pfu[is][jc][2] = y0; pfu[is][jc][3] = y1;                          \
        }                                                                      \
    __builtin_amdgcn_s_setprio(1);                                             \
    _Pragma("unroll") for (int jc = 0; jc < 2; ++jc) {                         \
        bf16x8 pa0 = __builtin_bit_cast(bf16x8, pfu[0][jc]);                   \
        bf16x8 pa1 = __builtin_bit_cast(bf16x8, pfu[1][jc]);                   \
        _Pragma("unroll") for (int cc = 0; cc < 3; ++cc) {                     \
            bf16x8 vf = *(const bf16x8*)(Vc + (cc * 32 + l31) * 64 +           \
                          ((((VHALF) * 4 + jc * 2 + hi) ^ (l31 & 7)) << 3));   \
            O[0][cc] = __builtin_amdgcn_mfma_f32_32x32x16_bf16(pa0, vf, O[0][cc], 0, 0, 0); \
            O[1][cc] = __builtin_amdgcn_mfma_f32_32x32x16_bf16(pa1, vf, O[1][cc], 0, 0, 0); \
        }                                                                      \
        Lon[0] = __builtin_amdgcn_mfma_f32_32x32x16_bf16(pa0, onef, Lon[0], 0, 0, 0); \
        Lon[1] = __builtin_amdgcn_mfma_f32_32x32x16_bf16(pa1, onef, Lon[1], 0, 0, 0); \
    }                                                                          \
    __builtin_amdgcn_s_setprio(0);                                             \
} while (0)

    int kb = 0, kb1 = 1, kb2 = 2;
    for (int tt = 0; tt < 32; tt += 2) {
        // ---- even sub-iter: tile tt, window tt/2, half 0
        {
            const int pfk = (tt + 2 < 32) ? tt + 2 : 31;
            STAGE_K(pfk, kb2);
            const int wn = (tt >> 1) + 1;
            const int pfw = (wn < 16) ? wn : 15;
            STAGE_V(pfw, wn & 1);
            BODY(kb, (tt >> 1) & 1, 0);
            asm volatile("s_waitcnt vmcnt(5)" ::: "memory");
            __builtin_amdgcn_s_barrier();
        }
        // ---- odd sub-iter: tile tt+1, window tt/2, half 1
        {
            const int pfk = (tt + 3 < 32) ? tt + 3 : 31;
            STAGE_K(pfk, kb);
            BODY(kb1, (tt >> 1) & 1, 1);
            asm volatile("s_waitcnt vmcnt(2)" ::: "memory");
            __builtin_amdgcn_s_barrier();
        }
        const int tmp = kb;
        kb = kb2; kb2 = kb1; kb1 = tmp;
    }
#undef BODY
#undef STAGE_K
#undef STAGE_V

    asm volatile("s_waitcnt vmcnt(0)" ::: "memory");

    // ---- epilogue: unnormalized O (bf16) + row sums (from Lon)
    unsigned short* zb = zp + ((size_t)js * 8 + n) * HW * CMID;
    #pragma unroll
    for (int is = 0; is < 2; ++is)
        #pragma unroll
        for (int cc = 0; cc < 3; ++cc)
            #pragma unroll
            for (int r = 0; r < 16; ++r) {
                int i = ib + is * 32 + (r & 3) + 8 * (r >> 2) + 4 * hi;
                zb[(size_t)i * CMID + cc * 32 + l31] = f2bf(O[is][cc][r]);
            }

    if (l31 == 0) {
        float* lb = lp + ((size_t)js * 8 + n) * HW;
        #pragma unroll
        for (int is = 0; is < 2; ++is)
            #pragma unroll
            for (int r = 0; r < 16; ++r) {
                int i = ib + is * 32 + (r & 3) + 8 * (r >> 2) + 4 * hi;
                lb[i] = Lon[is][r];
            }
    }
}

// ---------------------------------------------------------------------------
// Kernel 3: combine 4 j-slices, normalize, project back (MFMA), residual.
// R6-proven structure (2-D grid, b128 combine), JS=4.
// ---------------------------------------------------------------------------
__global__ __launch_bounds__(256) void zproj_kernel(
    const unsigned short* __restrict__ zp, const float* __restrict__ lp,
    const unsigned short* __restrict__ wzb, const float* __restrict__ bz,
    const float* __restrict__ x, const float* __restrict__ pe,
    float* __restrict__ out)
{
    const int n = blockIdx.y, i0 = blockIdx.x * 64, t = threadIdx.x;
    __shared__ unsigned short zt[64 * 104];
    __shared__ float ll[64];

    if (t < 64) {
        float s = 0.f;
        #pragma unroll
        for (int sl = 0; sl < 4; ++sl)
            s += lp[(size_t)sl * 8 * HW + (size_t)n * HW + i0 + t];
        ll[t] = 1.f / s;
    }
    __syncthreads();

    // combine: 768 units of (pixel, 8-channel group); b128 loads, shift-unpack
    #pragma unroll
    for (int u = 0; u < 3; ++u) {
        int unit = t + u * 256;           // 0..767
        int i = unit / 12, g = unit % 12;
        size_t gidx = ((size_t)n * HW + i0 + i) * CMID + g * 8;
        float a[8];
        #pragma unroll
        for (int e = 0; e < 8; ++e) a[e] = 0.f;
        #pragma unroll
        for (int sl = 0; sl < 4; ++sl) {
            u32x4 wv = *(const u32x4*)(zp + (size_t)sl * 8 * HW * CMID + gidx);
            #pragma unroll
            for (int k = 0; k < 4; ++k) {
                union { unsigned u; float f; } lo, hi2;
                lo.u = wv[k] << 16;
                hi2.u = wv[k] & 0xffff0000u;
                a[2 * k]     += lo.f;
                a[2 * k + 1] += hi2.f;
            }
        }
        float li = ll[i];
        unsigned ww[4];
        #pragma unroll
        for (int k = 0; k < 4; ++k) {
            float p0 = a[2 * k] * li, p1 = a[2 * k + 1] * li;
            asm("v_cvt_pk_bf16_f32 %0, %1, %2" : "=v"(ww[k]) : "v"(p0), "v"(p1));
        }
        u32x4 wv4 = {ww[0], ww[1], ww[2], ww[3]};
        *(u32x4*)(zt + i * 104 + g * 8) = wv4;
    }
    __syncthreads();

    const int w = t >> 6, lane = t & 63, l15 = lane & 15, lg = lane >> 4;
    const int p0 = w * 16;

    bf16x8 af[3];
    #pragma unroll
    for (int f = 0; f < 3; ++f)
        af[f] = *(const bf16x8*)(zt + (p0 + l15) * 104 + f * 32 + lg * 8);

    #pragma unroll
    for (int ct = 0; ct < 12; ++ct) {
        f32x4 acc = (f32x4){0.f, 0.f, 0.f, 0.f};
        const unsigned short* wrow = wzb + (ct * 16 + l15) * CMID + lg * 8;
        #pragma unroll
        for (int f = 0; f < 3; ++f) {
            bf16x8 wf = *(const bf16x8*)(wrow + f * 32);
            acc = __builtin_amdgcn_mfma_f32_16x16x32_bf16(af[f], wf, acc, 0, 0, 0);
        }
        const int co = ct * 16 + l15;
        const int ibase = i0 + p0 + lg * 4;
        size_t xa = ((size_t)n * CIN + co) * HW + ibase;
        f32x4 xv = *(const f32x4*)(x + xa);
        f32x4 pv = *(const f32x4*)(pe + co * 14400 + blockIdx.x * 120 + p0 + lg * 4);
        const float bias = bz[co];
        f32x4 o;
        #pragma unroll
        for (int r = 0; r < 4; ++r) o[r] = xv[r] + pv[r] + acc[r] + bias;
        *(f32x4*)(out + xa) = o;
    }
}

// ---------------------------------------------------------------------------
extern "C" void kernel_launch(void* const* d_in, const int* in_sizes, int n_in,
                              void* d_out, int out_size, void* d_ws, size_t ws_size,
                              hipStream_t stream) {
    const float* x  = (const float*)d_in[0];
    const float* pe = (const float*)d_in[1];
    const float* wq = (const float*)d_in[2];
    const float* bq = (const float*)d_in[3];
    const float* wk = (const float*)d_in[4];
    const float* bk = (const float*)d_in[5];
    const float* wv = (const float*)d_in[6];
    const float* bv = (const float*)d_in[7];
    const float* wz = (const float*)d_in[8];
    const float* bz = (const float*)d_in[9];
    float* out = (float*)d_out;

    char* ws = (char*)d_ws;
    // ws layout (bytes) — JS=4 (R5/R7-proven):
    //        0: wqkvb bf16 [288][192]          110,592 (pad 131072)
    //   131072: wzb   bf16 [192][96]            36,864 (pad 65536)
    //   196608: Q bf16 [8][4096][96]          6,291,456
    //  6488064: K bf16                        6,291,456
    // 12779520: V^T bf16 [8][96][4096]        6,291,456
    // 19070976: zp bf16 [4][8][4096][96]     25,165,824
    // 44236800: lp f32 [4][8][4096]             524,288   (end 44,761,088)
    unsigned short* wqkvb = (unsigned short*)(ws);
    unsigned short* wzb   = (unsigned short*)(ws + 131072);
    unsigned short* Qb    = (unsigned short*)(ws + 196608);
    unsigned short* Kb    = (unsigned short*)(ws + 6488064);
    unsigned short* Vb    = (unsigned short*)(ws + 12779520);
    unsigned short* zpb   = (unsigned short*)(ws + 19070976);
    float*          lpb   = (float*)(ws + 44236800);

    convw_kernel<<<288, 256, 0, stream>>>(wq, wk, wv, wz, wqkvb, wzb);
    qkv_kernel<<<dim3(64, 8), 512, 0, stream>>>(x, pe, wqkvb, bq, bk, bv,
                                                Qb, Kb, Vb);
    attn_kernel<<<512, 256, 0, stream>>>(Qb, Kb, Vb, zpb, lpb);
    zproj_kernel<<<dim3(64, 8), 256, 0, stream>>>(zpb, lpb, wzb, bz, x, pe, out);
}

// Round 10
// 125.721 us; speedup vs baseline: 1.3543x; 1.0078x over previous
//
#include <hip/hip_runtime.h>
#include <hip/hip_bf16.h>

#define HW 4096
#define CIN 192
#define CMID 96

typedef __attribute__((ext_vector_type(8))) short bf16x8;
typedef __attribute__((ext_vector_type(4))) float f32x4;
typedef __attribute__((ext_vector_type(16))) float f32x16;
typedef __attribute__((ext_vector_type(4))) unsigned int u32x4;
typedef __attribute__((ext_vector_type(2))) unsigned int u32x2;

static __device__ __forceinline__ unsigned short f2bf(float f) {
    union { float f; unsigned int u; } v;
    v.f = f;
    unsigned int r = v.u + 0x7fffu + ((v.u >> 16) & 1u);
    return (unsigned short)(r >> 16);
}

static __device__ __forceinline__ void gload16(const void* g, void* l) {
    __builtin_amdgcn_global_load_lds(
        (const __attribute__((address_space(1))) unsigned int*)g,
        (__attribute__((address_space(3))) unsigned int*)l, 16, 0, 0);
}

// (1/64) * log2(e), folded into Q at projection time
#define SCQ (0.015625f * 1.44269504089f)

// ---------------------------------------------------------------------------
// Kernel 0: convert weights to bf16.
// ---------------------------------------------------------------------------
__global__ __launch_bounds__(256) void convw_kernel(
    const float* __restrict__ wq, const float* __restrict__ wk,
    const float* __restrict__ wv, const float* __restrict__ wz,
    unsigned short* __restrict__ wqkvb, unsigned short* __restrict__ wzb)
{
    int idx = blockIdx.x * 256 + threadIdx.x;
    if (idx < 3 * CMID * CIN) {
        int m = idx / (CMID * CIN), r = idx % (CMID * CIN);
        const float* w = (m == 0) ? wq : ((m == 1) ? wk : wv);
        wqkvb[idx] = f2bf(w[r]);
    } else if (idx < 3 * CMID * CIN + CIN * CMID) {
        int r = idx - 3 * CMID * CIN;
        wzb[r] = f2bf(wz[r]);
    }
}

// ---------------------------------------------------------------------------
// Kernel 1: Q/K/V projections (bf16 MFMA).  Unchanged from R9.
// ---------------------------------------------------------------------------
__global__ __launch_bounds__(512) void qkv_kernel(
    const float* __restrict__ x, const float* __restrict__ pe,
    const unsigned short* __restrict__ wqkvb,
    const float* __restrict__ bq, const float* __restrict__ bk,
    const float* __restrict__ bv,
    unsigned short* __restrict__ Q, unsigned short* __restrict__ K,
    unsigned short* __restrict__ V)
{
    const int n = blockIdx.y, bx = blockIdx.x, i0 = bx * 64, t = threadIdx.x;
    __shared__ unsigned short xt[64 * 200];

    #pragma unroll
    for (int it = 0; it < 6; ++it) {
        int q = t + it * 512;
        int c = q >> 4, il4 = (q & 15) << 2;
        f32x4 xv = *(const f32x4*)(x + ((size_t)n * CIN + c) * HW + i0 + il4);
        f32x4 pv = *(const f32x4*)(pe + c * 14400 + bx * 120 + il4);
        float a0 = xv[0] + pv[0], a1 = xv[1] + pv[1];
        float a2 = xv[2] + pv[2], a3 = xv[3] + pv[3];
        unsigned w01, w23;
        asm("v_cvt_pk_bf16_f32 %0, %1, %2" : "=v"(w01) : "v"(a0), "v"(a1));
        asm("v_cvt_pk_bf16_f32 %0, %1, %2" : "=v"(w23) : "v"(a2), "v"(a3));
        xt[(il4 + 0) * 200 + c] = (unsigned short)w01;
        xt[(il4 + 1) * 200 + c] = (unsigned short)(w01 >> 16);
        xt[(il4 + 2) * 200 + c] = (unsigned short)w23;
        xt[(il4 + 3) * 200 + c] = (unsigned short)(w23 >> 16);
    }
    __syncthreads();

    const int w = t >> 6, lane = t & 63, l15 = lane & 15, lg = lane >> 4;
    const int wg = w >> 2;
    const int p0 = (w & 3) * 16;

    bf16x8 af[6];
    #pragma unroll
    for (int f = 0; f < 6; ++f)
        af[f] = *(const bf16x8*)(xt + (p0 + l15) * 200 + f * 32 + lg * 8);

    #pragma unroll
    for (int cc = 0; cc < 9; ++cc) {
        const int ct = wg * 9 + cc;
        const int m = ct / 6, c6 = ct % 6;
        f32x4 acc = (f32x4){0.f, 0.f, 0.f, 0.f};
        const unsigned short* wrow = wqkvb + (ct * 16 + l15) * CIN + lg * 8;
        #pragma unroll
        for (int f = 0; f < 6; ++f) {
            bf16x8 wf = *(const bf16x8*)(wrow + f * 32);
            if (m < 2)
                acc = __builtin_amdgcn_mfma_f32_16x16x32_bf16(wf, af[f], acc, 0, 0, 0);
            else
                acc = __builtin_amdgcn_mfma_f32_16x16x32_bf16(af[f], wf, acc, 0, 0, 0);
        }
        if (m < 2) {
            f32x4 bv4 = *(const f32x4*)(((m == 0) ? bq : bk) + c6 * 16 + lg * 4);
            ushort4 pk4;
            if (m == 0) {
                pk4.x = f2bf((acc[0] + bv4[0]) * SCQ);
                pk4.y = f2bf((acc[1] + bv4[1]) * SCQ);
                pk4.z = f2bf((acc[2] + bv4[2]) * SCQ);
                pk4.w = f2bf((acc[3] + bv4[3]) * SCQ);
            } else {
                pk4.x = f2bf(acc[0] + bv4[0]);
                pk4.y = f2bf(acc[1] + bv4[1]);
                pk4.z = f2bf(acc[2] + bv4[2]);
                pk4.w = f2bf(acc[3] + bv4[3]);
            }
            unsigned short* dst = ((m == 0) ? Q : K) + (size_t)n * HW * CMID;
            *(ushort4*)(dst + (size_t)(i0 + p0 + l15) * CMID + c6 * 16 + lg * 4) = pk4;
        } else {
            const float bias = bv[c6 * 16 + l15];
            ushort4 pk4;
            pk4.x = f2bf(acc[0] + bias); pk4.y = f2bf(acc[1] + bias);
            pk4.z = f2bf(acc[2] + bias); pk4.w = f2bf(acc[3] + bias);
            *(ushort4*)(V + (size_t)n * CMID * HW + (size_t)(c6 * 16 + l15) * HW
                          + i0 + p0 + lg * 4) = pk4;
        }
    }
}

// ---------------------------------------------------------------------------
// Kernel 2: attention core.  64 q-rows/wave; 32-j K tiles in 4 LDS buffers;
// 64-j V windows double-buffered.  TWO BODIES per sync region: one
// vmcnt(0)+s_barrier per 2 tiles (stage->wait distance ~2 bodies >> L2
// latency, so the drain is cheap).  In-register softmax; permlane32_swap;
// MFMA row-sums.  n == XCD pinning, grid 512 all-resident at 2 blocks/CU.
// ---------------------------------------------------------------------------
__global__ __launch_bounds__(256, 2) void attn_kernel(
    const unsigned short* __restrict__ Q, const unsigned short* __restrict__ K,
    const unsigned short* __restrict__ V,
    unsigned short* __restrict__ zp, float* __restrict__ lp)
{
    const int bid = blockIdx.x;           // 512 = 8 n * 16 iblk * 4 js
    const int n    = bid & 7;             // n == XCD: K/V L2-resident per XCD
    const int iblk = (bid >> 3) & 15;
    const int js   = bid >> 7;            // 0..3

    const int t = threadIdx.x, w = t >> 6, lane = t & 63;
    const int l31 = lane & 31, hi = lane >> 5;
    const int ib = iblk * 256 + w * 64;   // first of 64 q-rows for this wave

    __shared__ unsigned short Ks[4][32 * 128];  // 4 x 8 KB
    __shared__ unsigned short Vs[2][96 * 64];   // 2 x 12 KB  (56 KB total)

    const unsigned short* Qb = Q + (size_t)n * HW * CMID;
    const unsigned short* Kb = K + (size_t)n * HW * CMID;
    const unsigned short* Vb = V + (size_t)n * CMID * HW;

    // Q as B-frag: col = i, k = kc*16 + hi*8 + e
    bf16x8 qf[2][6];
    #pragma unroll
    for (int is = 0; is < 2; ++is)
        #pragma unroll
        for (int kc = 0; kc < 6; ++kc)
            qf[is][kc] = *(const bf16x8*)(Qb + (size_t)(ib + is * 32 + l31) * CMID
                                            + kc * 16 + hi * 8);

    // staging source offsets, pre-swizzled (involution: granule ^= row&7)
    int ksoff[2], vsoff[3];
    #pragma unroll
    for (int s = 0; s < 2; ++s) {
        int row = 8 * w + 4 * s + (lane >> 4);           // 0..31
        ksoff[s] = row * CMID + (((lane & 15) ^ (row & 7)) * 8);
    }
    #pragma unroll
    for (int s = 0; s < 3; ++s) {
        int c = 8 * (w * 3 + s) + (lane >> 3);           // 0..95
        vsoff[s] = c * HW + (((lane & 7) ^ (c & 7)) * 8);
    }

    const int j00 = js * 1024;

#define STAGE_K(TILE, KB) do {                                                 \
    _Pragma("unroll") for (int s = 0; s < 2; ++s)                              \
        gload16(Kb + (size_t)(j00 + (TILE) * 32) * CMID + ksoff[s],            \
                &Ks[KB][(w * 2 + s) * 512]);                                   \
} while (0)
#define STAGE_V(WND, VB) do {                                                  \
    _Pragma("unroll") for (int s = 0; s < 3; ++s)                              \
        gload16(Vb + (size_t)(j00 + (WND) * 64) + vsoff[s],                    \
                &Vs[VB][(w * 3 + s) * 512]);                                   \
} while (0)

    f32x16 O[2][3], Lon[2];
    #pragma unroll
    for (int is = 0; is < 2; ++is) {
        #pragma unroll
        for (int cc = 0; cc < 3; ++cc)
            #pragma unroll
            for (int e = 0; e < 16; ++e) O[is][cc][e] = 0.f;
        #pragma unroll
        for (int e = 0; e < 16; ++e) Lon[is][e] = 0.f;
    }

    bf16x8 onef;
    #pragma unroll
    for (int e = 0; e < 8; ++e) onef[e] = (short)0x3F80;  // bf16 1.0

    STAGE_K(0, 0);
    STAGE_K(1, 1);
    STAGE_V(0, 0);
    asm volatile("s_waitcnt vmcnt(0)" ::: "memory");
    __builtin_amdgcn_s_barrier();

#define BODY(KBUF, VBUF, VHALF) do {                                           \
    const unsigned short* Kc = &Ks[KBUF][0];                                   \
    const unsigned short* Vc = &Vs[VBUF][0];                                   \
    f32x16 s0, s1;                                                             \
    _Pragma("unroll") for (int e = 0; e < 16; ++e) { s0[e] = 0.f; s1[e] = 0.f; } \
    __builtin_amdgcn_s_setprio(1);                                             \
    _Pragma("unroll") for (int kc = 0; kc < 6; ++kc) {                         \
        bf16x8 kf = *(const bf16x8*)(Kc + l31 * 128 +                          \
                      (((kc * 2 + hi) ^ (l31 & 7)) << 3));                     \
        s0 = __builtin_amdgcn_mfma_f32_32x32x16_bf16(kf, qf[0][kc], s0, 0, 0, 0); \
        s1 = __builtin_amdgcn_mfma_f32_32x32x16_bf16(kf, qf[1][kc], s1, 0, 0, 0); \
    }                                                                          \
    __builtin_amdgcn_s_setprio(0);                                             \
    unsigned pkk[2][4][2];                                                     \
    _Pragma("unroll") for (int q = 0; q < 4; ++q)                              \
        _Pragma("unroll") for (int rp = 0; rp < 2; ++rp) {                     \
            float lo0 = __builtin_exp2f(s0[q * 4 + 2 * rp]);                   \
            float hh0 = __builtin_exp2f(s0[q * 4 + 2 * rp + 1]);               \
            float lo1 = __builtin_exp2f(s1[q * 4 + 2 * rp]);                   \
            float hh1 = __builtin_exp2f(s1[q * 4 + 2 * rp + 1]);               \
            asm("v_cvt_pk_bf16_f32 %0, %1, %2"                                 \
                : "=v"(pkk[0][q][rp]) : "v"(lo0), "v"(hh0));                   \
            asm("v_cvt_pk_bf16_f32 %0, %1, %2"                                 \
                : "=v"(pkk[1][q][rp]) : "v"(lo1), "v"(hh1));                   \
        }                                                                      \
    u32x4 pfu[2][2];                                                           \
    _Pragma("unroll") for (int is = 0; is < 2; ++is)                           \
        _Pragma("unroll") for (int jc = 0; jc < 2; ++jc) {                     \
            unsigned x0 = pkk[is][2 * jc][0], y0 = pkk[is][2 * jc + 1][0];     \
            unsigned x1 = pkk[is][2 * jc][1], y1 = pkk[is][2 * jc + 1][1];     \
            asm("v_permlane32_swap_b32 %0, %1" : "+v"(y0), "+v"(x0));          \
            asm("v_permlane32_swap_b32 %0, %1" : "+v"(y1), "+v"(x1));          \
            pfu[is][jc][0] = x0; pfu[is][jc][1] = x1;                          \
            pfu[is][jc][2] = y0; pfu[is][jc][3] = y1;                          \
        }                                                                      \
    __builtin_amdgcn_s_setprio(1);                                             \
    _Pragma("unroll") for (int jc = 0; jc < 2; ++jc) {                         \
        bf16x8 pa0 = __builtin_bit_cast(bf16x8, pfu[0][jc]);                   \
        bf16x8 pa1 = __builtin_bit_cast(bf16x8, pfu[1][jc]);                   \
        _Pragma("unroll") for (int cc = 0; cc < 3; ++cc) {                     \
            bf16x8 vf = *(const bf16x8*)(Vc + (cc * 32 + l31) * 64 +           \
                          ((((VHALF) * 4 + jc * 2 + hi) ^ (l31 & 7)) << 3));   \
            O[0][cc] = __builtin_amdgcn_mfma_f32_32x32x16_bf16(pa0, vf, O[0][cc], 0, 0, 0); \
            O[1][cc] = __builtin_amdgcn_mfma_f32_32x32x16_bf16(pa1, vf, O[1][cc], 0, 0, 0); \
        }                                                                      \
        Lon[0] = __builtin_amdgcn_mfma_f32_32x32x16_bf16(pa0, onef, Lon[0], 0, 0, 0); \
        Lon[1] = __builtin_amdgcn_mfma_f32_32x32x16_bf16(pa1, onef, Lon[1], 0, 0, 0); \
    }                                                                          \
    __builtin_amdgcn_s_setprio(0);                                             \
} while (0)

    // 8 iterations x 2 regions x 2 bodies; all buffer indices compile-time.
    for (int tt = 0; tt < 32; tt += 4) {
        // ---- region A: compute tiles tt, tt+1 (K bufs 0,1; V buf 0)
        {
            STAGE_K(tt + 2, 2);
            STAGE_K(tt + 3, 3);
            const int wn = (tt >> 1) + 1;
            STAGE_V((wn < 16) ? wn : 15, 1);
            BODY(0, 0, 0);
            BODY(1, 0, 1);
            asm volatile("s_waitcnt vmcnt(0)" ::: "memory");
            __builtin_amdgcn_s_barrier();
        }
        // ---- region B: compute tiles tt+2, tt+3 (K bufs 2,3; V buf 1)
        {
            const int k4 = (tt + 4 < 32) ? tt + 4 : 31;
            const int k5 = (tt + 5 < 32) ? tt + 5 : 31;
            STAGE_K(k4, 0);
            STAGE_K(k5, 1);
            const int wn = (tt >> 1) + 2;
            STAGE_V((wn < 16) ? wn : 15, 0);
            BODY(2, 1, 0);
            BODY(3, 1, 1);
            asm volatile("s_waitcnt vmcnt(0)" ::: "memory");
            __builtin_amdgcn_s_barrier();
        }
    }
#undef BODY
#undef STAGE_K
#undef STAGE_V

    // ---- epilogue: unnormalized O (bf16) + row sums (from Lon)
    unsigned short* zb = zp + ((size_t)js * 8 + n) * HW * CMID;
    #pragma unroll
    for (int is = 0; is < 2; ++is)
        #pragma unroll
        for (int cc = 0; cc < 3; ++cc)
            #pragma unroll
            for (int r = 0; r < 16; ++r) {
                int i = ib + is * 32 + (r & 3) + 8 * (r >> 2) + 4 * hi;
                zb[(size_t)i * CMID + cc * 32 + l31] = f2bf(O[is][cc][r]);
            }

    if (l31 == 0) {
        float* lb = lp + ((size_t)js * 8 + n) * HW;
        #pragma unroll
        for (int is = 0; is < 2; ++is)
            #pragma unroll
            for (int r = 0; r < 16; ++r) {
                int i = ib + is * 32 + (r & 3) + 8 * (r >> 2) + 4 * hi;
                lb[i] = Lon[is][r];
            }
    }
}

// ---------------------------------------------------------------------------
// Kernel 3: combine 4 j-slices, normalize, project back (MFMA), residual.
// Unchanged from R9.
// ---------------------------------------------------------------------------
__global__ __launch_bounds__(256) void zproj_kernel(
    const unsigned short* __restrict__ zp, const float* __restrict__ lp,
    const unsigned short* __restrict__ wzb, const float* __restrict__ bz,
    const float* __restrict__ x, const float* __restrict__ pe,
    float* __restrict__ out)
{
    const int n = blockIdx.y, i0 = blockIdx.x * 64, t = threadIdx.x;
    __shared__ unsigned short zt[64 * 104];
    __shared__ float ll[64];

    if (t < 64) {
        float s = 0.f;
        #pragma unroll
        for (int sl = 0; sl < 4; ++sl)
            s += lp[(size_t)sl * 8 * HW + (size_t)n * HW + i0 + t];
        ll[t] = 1.f / s;
    }
    __syncthreads();

    #pragma unroll
    for (int u = 0; u < 3; ++u) {
        int unit = t + u * 256;
        int i = unit / 12, g = unit % 12;
        size_t gidx = ((size_t)n * HW + i0 + i) * CMID + g * 8;
        float a[8];
        #pragma unroll
        for (int e = 0; e < 8; ++e) a[e] = 0.f;
        #pragma unroll
        for (int sl = 0; sl < 4; ++sl) {
            u32x4 wv = *(const u32x4*)(zp + (size_t)sl * 8 * HW * CMID + gidx);
            #pragma unroll
            for (int k = 0; k < 4; ++k) {
                union { unsigned u; float f; } lo, hi2;
                lo.u = wv[k] << 16;
                hi2.u = wv[k] & 0xffff0000u;
                a[2 * k]     += lo.f;
                a[2 * k + 1] += hi2.f;
            }
        }
        float li = ll[i];
        unsigned ww[4];
        #pragma unroll
        for (int k = 0; k < 4; ++k) {
            float p0 = a[2 * k] * li, p1 = a[2 * k + 1] * li;
            asm("v_cvt_pk_bf16_f32 %0, %1, %2" : "=v"(ww[k]) : "v"(p0), "v"(p1));
        }
        u32x4 wv4 = {ww[0], ww[1], ww[2], ww[3]};
        *(u32x4*)(zt + i * 104 + g * 8) = wv4;
    }
    __syncthreads();

    const int w = t >> 6, lane = t & 63, l15 = lane & 15, lg = lane >> 4;
    const int p0 = w * 16;

    bf16x8 af[3];
    #pragma unroll
    for (int f = 0; f < 3; ++f)
        af[f] = *(const bf16x8*)(zt + (p0 + l15) * 104 + f * 32 + lg * 8);

    #pragma unroll
    for (int ct = 0; ct < 12; ++ct) {
        f32x4 acc = (f32x4){0.f, 0.f, 0.f, 0.f};
        const unsigned short* wrow = wzb + (ct * 16 + l15) * CMID + lg * 8;
        #pragma unroll
        for (int f = 0; f < 3; ++f) {
            bf16x8 wf = *(const bf16x8*)(wrow + f * 32);
            acc = __builtin_amdgcn_mfma_f32_16x16x32_bf16(af[f], wf, acc, 0, 0, 0);
        }
        const int co = ct * 16 + l15;
        const int ibase = i0 + p0 + lg * 4;
        size_t xa = ((size_t)n * CIN + co) * HW + ibase;
        f32x4 xv = *(const f32x4*)(x + xa);
        f32x4 pv = *(const f32x4*)(pe + co * 14400 + blockIdx.x * 120 + p0 + lg * 4);
        const float bias = bz[co];
        f32x4 o;
        #pragma unroll
        for (int r = 0; r < 4; ++r) o[r] = xv[r] + pv[r] + acc[r] + bias;
        *(f32x4*)(out + xa) = o;
    }
}

// ---------------------------------------------------------------------------
extern "C" void kernel_launch(void* const* d_in, const int* in_sizes, int n_in,
                              void* d_out, int out_size, void* d_ws, size_t ws_size,
                              hipStream_t stream) {
    const float* x  = (const float*)d_in[0];
    const float* pe = (const float*)d_in[1];
    const float* wq = (const float*)d_in[2];
    const float* bq = (const float*)d_in[3];
    const float* wk = (const float*)d_in[4];
    const float* bk = (const float*)d_in[5];
    const float* wv = (const float*)d_in[6];
    const float* bv = (const float*)d_in[7];
    const float* wz = (const float*)d_in[8];
    const float* bz = (const float*)d_in[9];
    float* out = (float*)d_out;

    char* ws = (char*)d_ws;
    // ws layout (bytes) — JS=4 (R5/R7/R9-proven):
    //        0: wqkvb bf16 [288][192]          110,592 (pad 131072)
    //   131072: wzb   bf16 [192][96]            36,864 (pad 65536)
    //   196608: Q bf16 [8][4096][96]          6,291,456
    //  6488064: K bf16                        6,291,456
    // 12779520: V^T bf16 [8][96][4096]        6,291,456
    // 19070976: zp bf16 [4][8][4096][96]     25,165,824
    // 44236800: lp f32 [4][8][4096]             524,288   (end 44,761,088)
    unsigned short* wqkvb = (unsigned short*)(ws);
    unsigned short* wzb   = (unsigned short*)(ws + 131072);
    unsigned short* Qb    = (unsigned short*)(ws + 196608);
    unsigned short* Kb    = (unsigned short*)(ws + 6488064);
    unsigned short* Vb    = (unsigned short*)(ws + 12779520);
    unsigned short* zpb   = (unsigned short*)(ws + 19070976);
    float*          lpb   = (float*)(ws + 44236800);

    convw_kernel<<<288, 256, 0, stream>>>(wq, wk, wv, wz, wqkvb, wzb);
    qkv_kernel<<<dim3(64, 8), 512, 0, stream>>>(x, pe, wqkvb, bq, bk, bv,
                                                Qb, Kb, Vb);
    attn_kernel<<<512, 256, 0, stream>>>(Qb, Kb, Vb, zpb, lpb);
    zproj_kernel<<<dim3(64, 8), 256, 0, stream>>>(zpb, lpb, wzb, bz, x, pe, out);
}